// Round 15
// baseline (189.848 us; speedup 1.0000x reference)
//
#include <hip/hip_runtime.h>
#include <stdint.h>

// PressureLSTM: B=4096, T=512, F=32, H=32, gates=128 (i,f,g,o).
// Swapped-MFMA, permuted gate index pg = e*4 + gtype (verified r5-r14):
//   mfma(A=W', B=X^T/H^T); lane's 4 acc regs = i,f,g,o of
//   (element e=4*wv+q, batch row col) -> lane-local cell update.
// r15 (from r11 base = 137us; r14's raw-barrier regressed -> plain barrier):
//   GRID 512 / 8 REAL ROWS PER BLOCK. r11's occupancy (22.8% = 7.3 waves/CU)
//   revealed grid 256 = exactly 1 block/CU: all 8 waves barrier-locked, the
//   post-barrier chain stall idles the whole CU. With 8-row blocks there are
//   2 co-resident blocks/CU whose phases interleave. MFMA cols 8..15 (and
//   their elementwise + hs writes) duplicate rows 0..7 into hs rows 8..15,
//   so the B-fragment read pattern is unchanged. Duplication adds ~90 issue
//   cyc/step (cheap now: step is 2 MFMA + 7 trans) for real latency overlap.
//   Otherwise identical to r11: xs[4] ring staged 3 ahead, a1c C-operand
//   x-projection, f16 weights pre-scaled -log2e/+2log2e, single-rcp fused
//   c-update, c clamped +-16, one __syncthreads per step.

typedef _Float16 half8 __attribute__((ext_vector_type(8)));
typedef __attribute__((ext_vector_type(4))) float float4v;

#define T_LEN 512
#define B_ALL 4096
#define RROWS 8               // real rows per block
#define NBLK (B_ALL / RROWS)  // 512 blocks -> 2 blocks/CU
#define P 40                  // f16 per LDS row (80 B pitch, b128-aligned)

__global__ __launch_bounds__(512, 4) void lstm_fused_kernel(
    const float* __restrict__ x,     // [B, T, 32]
    const float* __restrict__ W_ih,  // [128, 32]
    const float* __restrict__ W_hh,  // [128, 32]
    const float* __restrict__ b_ih,  // [128]
    const float* __restrict__ b_hh,  // [128]
    const float* __restrict__ W_fc,  // [1, 32]
    const float* __restrict__ b_fc,  // [1]
    float* __restrict__ out)         // [B]
{
    const int tid  = threadIdx.x;    // 0..511
    const int wv   = tid >> 6;       // wave 0..7 (gate tile wv)
    const int lane = tid & 63;
    const int col  = lane & 15;      // hs row; cols 8..15 duplicate rows 0..7
    const int q    = lane >> 4;      // 0..3
    const int k0   = q * 8;
    const int b0   = blockIdx.x * RROWS;
    const int e    = 4 * wv + q;     // this lane's h element (0..31)

    __shared__ __align__(16) _Float16 hs[2][16][P];
    __shared__ __align__(16) _Float16 xs[4][16][P];

    // ---- A-fragment weights, single f16 (RNE), pre-scaled per gate type:
    // lane holds W'[pg=16wv+col][k0..k0+7]; pg=e'*4+gt, e'=4wv+(col>>2), gt=col&3
    half8 wih, whh;
    {
        const int gt   = col & 3;
        const int gmem = gt * 32 + (4 * wv + (col >> 2));
        const float gs = (gt == 2) ? 2.88539008f : -1.44269504f;
        const float* wr = W_ih + gmem * 32 + k0;
        const float* hr = W_hh + gmem * 32 + k0;
        #pragma unroll
        for (int i = 0; i < 8; ++i) {
            wih[i] = (_Float16)(wr[i] * gs);
            whh[i] = (_Float16)(hr[i] * gs);
        }
    }
    // bias for acc reg r: gate type r of element e, same pre-scale
    float4v bias4;
    #pragma unroll
    for (int r = 0; r < 4; ++r) {
        const float gsr = (r == 2) ? 2.88539008f : -1.44269504f;
        bias4[r] = (b_ih[r * 32 + e] + b_hh[r * 32 + e]) * gsr;
    }

    float c = 0.f;

    // ---- x staging: 512 threads cover 16 LDS rows x 32 k (rows 8..15 are
    // duplicates of 0..7 -> same global source row, L1-absorbed).
    const int sr = tid >> 5;         // staged LDS row 0..15
    const int sk = tid & 31;         // k element
    const float* xsrc = x + ((size_t)(b0 + (sr & 7)) * T_LEN) * 32 + sk;

    // prologue: prime xs[0..2] with x(0..2); h(-1)=0; FIFO xA=x(3), xB=x(4)
    float xA, xB;
    {
        xs[0][sr][sk] = (_Float16)xsrc[0];
        xs[1][sr][sk] = (_Float16)xsrc[32];
        xs[2][sr][sk] = (_Float16)xsrc[64];
        hs[0][sr][sk] = (_Float16)0.f;
        xA = xsrc[3 * 32];
        xB = xsrc[4 * 32];
    }
    __syncthreads();

    // a1c for t=0 (x-side acc, bias folded as C)
    float4v a1c;
    {
        const half8 ax0 = *(const half8*)&xs[0][col][k0];
        a1c = __builtin_amdgcn_mfma_f32_16x16x32_f16(wih, ax0, bias4, 0, 0, 0);
    }

    // step t (hs parity PPAR=t&1): reads hs[PPAR], writes hs[PPAR^1].
    // xs ring: reads xs[(t+1)&3], writes xs[(t+3)&3] from XREG; reloads x(t+5).
    #define STEP(PPAR, XREG, TT)                                                \
    {                                                                           \
        const half8 ah = *(const half8*)&hs[PPAR][col][k0];   /* critical */    \
        const float4v acc =                                                     \
            __builtin_amdgcn_mfma_f32_16x16x32_f16(whh, ah, a1c, 0, 0, 0);      \
        /* next step's x-side acc (off critical path) */                        \
        const half8 axn = *(const half8*)&xs[((TT) + 1) & 3][col][k0];          \
        a1c = __builtin_amdgcn_mfma_f32_16x16x32_f16(wih, axn, bias4, 0, 0, 0); \
        {   /* stage x(TT+3) -> xs ring; reload XREG = x(TT+5) */               \
            xs[((TT) + 3) & 3][sr][sk] = (_Float16)XREG;                        \
            int tn = (TT) + 5; if (tn >= T_LEN) tn = T_LEN - 1;                 \
            XREG = xsrc[(size_t)tn * 32];                                       \
        }                                                                       \
        /* fused activations (single-rcp c-update):                          */ \
        /* c' = [c(1+Ai)(1+Bg) + (Bg-1)(1+Af)] * rcp((1+Af)(1+Ai)(1+Bg))    */  \
        const float Ai = __builtin_amdgcn_exp2f(acc[0]);                        \
        const float Af = __builtin_amdgcn_exp2f(acc[1]);                        \
        const float Bg = __builtin_amdgcn_exp2f(acc[2]);                        \
        const float Ao = __builtin_amdgcn_exp2f(acc[3]);                        \
        const float pI = 1.0f + Ai;                                             \
        const float pG = 1.0f + Bg;                                             \
        const float pF = 1.0f + Af;                                             \
        const float pIG = pI * pG;                                              \
        const float num = c * pIG + (Bg - 1.0f) * pF;                           \
        c = num * __builtin_amdgcn_rcpf(pF * pIG);                              \
        const float cc = fminf(fmaxf(c, -16.0f), 16.0f);                        \
        const float C2 = __builtin_amdgcn_exp2f(cc * 2.88539008f);              \
        const float r3 = __builtin_amdgcn_rcpf((1.0f + Ao) * (1.0f + C2));      \
        const float hv = (C2 - 1.0f) * r3;                                      \
        hs[PPAR ^ 1][col][e] = (_Float16)hv;                                    \
        __syncthreads();                                                        \
    }

    for (int t = 0; t < T_LEN; t += 2) {
        STEP(0, xA, t)
        STEP(1, xB, t + 1)
    }
    #undef STEP

    // ---- epilogue: h(511) was written to hs[0] (step 511 has parity 1)
    if (tid < RROWS) {
        float s = b_fc[0];
        #pragma unroll
        for (int cc2 = 0; cc2 < 32; ++cc2) {
            s += (float)hs[0][tid][cc2] * W_fc[cc2];
        }
        out[b0 + tid] = s;
    }
}

extern "C" void kernel_launch(void* const* d_in, const int* in_sizes, int n_in,
                              void* d_out, int out_size, void* d_ws, size_t ws_size,
                              hipStream_t stream) {
    const float* x    = (const float*)d_in[0];
    const float* W_ih = (const float*)d_in[1];
    const float* W_hh = (const float*)d_in[2];
    const float* b_ih = (const float*)d_in[3];
    const float* b_hh = (const float*)d_in[4];
    const float* W_fc = (const float*)d_in[5];
    const float* b_fc = (const float*)d_in[6];
    float* out = (float*)d_out;

    lstm_fused_kernel<<<dim3(NBLK), dim3(512), 0, stream>>>(
        x, W_ih, W_hh, b_ih, b_hh, W_fc, b_fc, out);
}

// Round 16
// 144.949 us; speedup vs baseline: 1.3098x; 1.3098x over previous
//
#include <hip/hip_runtime.h>
#include <stdint.h>

// PressureLSTM: B=4096, T=512, F=32, H=32, gates=128 (i,f,g,o).
// Swapped-MFMA, permuted gate index pg = e*4 + gtype (verified r5-r15):
//   mfma(A=W', B=X^T/H^T); lane's 4 acc regs = i,f,g,o of
//   (element e, batch row col) -> lane-local cell update.
// r16: 4 waves x 2 gate-tiles (wv, wv+4), 16 real rows, grid 256.
//   r15 falsified "idle CU": 2x occupancy + 2x VALUBusy => SLOWER. The CU's
//   LDS pipe (~370 of 640 cyc/step: 16 b128 reads + 16 writes + conflicts)
//   is the serializer. Each wave now reads ah/axn ONCE for both its tiles:
//   LDS reads per CU-step halve. Per-wave issue (~130cyc: 4 MFMA + 14 trans)
//   stays below the ~300cyc chain; 1 wave/SIMD keeps all SIMDs fed.
//   (This is r8's shape, retried on the LIGHT f16 step - r8's confound was
//   its heavy bf16x3 6-MFMA step.)
//   Otherwise identical to r11: xs[4] ring staged 3 ahead, parity FIFO,
//   a1c C-operand x-projection, f16 weights pre-scaled -log2e/+2log2e,
//   single-rcp fused c-update, c clamped +-16, one __syncthreads per step.

typedef _Float16 half8 __attribute__((ext_vector_type(8)));
typedef _Float16 half2v __attribute__((ext_vector_type(2)));
typedef __attribute__((ext_vector_type(4))) float float4v;
typedef __attribute__((ext_vector_type(2))) float float2v;

#define T_LEN 512
#define B_ALL 4096
#define ROWS 16
#define NBLK (B_ALL / ROWS)   // 256 blocks -> 1 block/CU
#define P 40                  // f16 per LDS row (80 B pitch, b128-aligned)

__global__ __launch_bounds__(256, 1) void lstm_fused_kernel(
    const float* __restrict__ x,     // [B, T, 32]
    const float* __restrict__ W_ih,  // [128, 32]
    const float* __restrict__ W_hh,  // [128, 32]
    const float* __restrict__ b_ih,  // [128]
    const float* __restrict__ b_hh,  // [128]
    const float* __restrict__ W_fc,  // [1, 32]
    const float* __restrict__ b_fc,  // [1]
    float* __restrict__ out)         // [B]
{
    const int tid  = threadIdx.x;    // 0..255
    const int wv   = tid >> 6;       // wave 0..3
    const int lane = tid & 63;
    const int col  = lane & 15;      // batch row within tile (all real)
    const int q    = lane >> 4;      // 0..3
    const int k0   = q * 8;
    const int b0   = blockIdx.x * ROWS;
    const int e0   = 4 * wv + q;     // tile-0 element (0..15)
    const int e1   = e0 + 16;        // tile-1 element (16..31)

    __shared__ __align__(16) _Float16 hs[2][ROWS][P];
    __shared__ __align__(16) _Float16 xs[4][ROWS][P];

    // ---- A-fragment weights for tiles wv, wv+4 (verified mapping), f16 RNE,
    // pre-scaled: i,f,o rows by -log2e (sigmoid via rcp(1+exp2)); g by +2log2e.
    half8 wih0, whh0, wih1, whh1;
    float4v bias0, bias1;
    {
        const int gt = col & 3;
        const float gs = (gt == 2) ? 2.88539008f : -1.44269504f;
        const int g0 = gt * 32 + (4 * wv + (col >> 2));
        const int g1 = gt * 32 + (4 * (wv + 4) + (col >> 2));
        const float* wr0 = W_ih + g0 * 32 + k0;
        const float* hr0 = W_hh + g0 * 32 + k0;
        const float* wr1 = W_ih + g1 * 32 + k0;
        const float* hr1 = W_hh + g1 * 32 + k0;
        #pragma unroll
        for (int i = 0; i < 8; ++i) {
            wih0[i] = (_Float16)(wr0[i] * gs);
            whh0[i] = (_Float16)(hr0[i] * gs);
            wih1[i] = (_Float16)(wr1[i] * gs);
            whh1[i] = (_Float16)(hr1[i] * gs);
        }
        #pragma unroll
        for (int r = 0; r < 4; ++r) {
            const float gsr = (r == 2) ? 2.88539008f : -1.44269504f;
            bias0[r] = (b_ih[r * 32 + e0] + b_hh[r * 32 + e0]) * gsr;
            bias1[r] = (b_ih[r * 32 + e1] + b_hh[r * 32 + e1]) * gsr;
        }
    }

    float c0 = 0.f, c1 = 0.f;

    // ---- x staging: 256 threads cover 16 rows x 32 k; each owns (sr, k2,k2+1)
    const int sr = tid >> 4;          // staged row 0..15
    const int k2 = (tid & 15) << 1;   // k pair base (even -> 4B-aligned)
    const float* xsrc = x + ((size_t)(b0 + sr) * T_LEN) * 32 + k2;

    // prologue: prime xs[0..2] = x(0..2); h(-1)=0; FIFO xA=x(3), xB=x(4)
    float2v xA, xB;
    {
        float2v v0 = *(const float2v*)(xsrc);
        float2v v1 = *(const float2v*)(xsrc + 32);
        float2v v2 = *(const float2v*)(xsrc + 64);
        half2v h0; h0[0] = (_Float16)v0[0]; h0[1] = (_Float16)v0[1];
        half2v h1; h1[0] = (_Float16)v1[0]; h1[1] = (_Float16)v1[1];
        half2v h2; h2[0] = (_Float16)v2[0]; h2[1] = (_Float16)v2[1];
        *(half2v*)&xs[0][sr][k2] = h0;
        *(half2v*)&xs[1][sr][k2] = h1;
        *(half2v*)&xs[2][sr][k2] = h2;
        half2v hz; hz[0] = (_Float16)0.f; hz[1] = (_Float16)0.f;
        *(half2v*)&hs[0][sr][k2] = hz;
        xA = *(const float2v*)(xsrc + 3 * 32);
        xB = *(const float2v*)(xsrc + 4 * 32);
    }
    __syncthreads();

    // a1c for t=0 (x-side accs, bias folded as C)
    float4v a1c0, a1c1;
    {
        const half8 ax0 = *(const half8*)&xs[0][col][k0];
        a1c0 = __builtin_amdgcn_mfma_f32_16x16x32_f16(wih0, ax0, bias0, 0, 0, 0);
        a1c1 = __builtin_amdgcn_mfma_f32_16x16x32_f16(wih1, ax0, bias1, 0, 0, 0);
    }

    // step t (hs parity PPAR=t&1): reads hs[PPAR], writes hs[PPAR^1].
    // xs ring: reads xs[(t+1)&3], writes xs[(t+3)&3] from XREG; reloads x(t+5).
    #define STEP(PPAR, XREG, TT)                                                \
    {                                                                           \
        const half8 ah = *(const half8*)&hs[PPAR][col][k0];   /* critical */    \
        const float4v acc0 =                                                    \
            __builtin_amdgcn_mfma_f32_16x16x32_f16(whh0, ah, a1c0, 0, 0, 0);    \
        const float4v acc1 =                                                    \
            __builtin_amdgcn_mfma_f32_16x16x32_f16(whh1, ah, a1c1, 0, 0, 0);    \
        /* next step's x-side accs (off critical path, one shared read) */      \
        const half8 axn = *(const half8*)&xs[((TT) + 1) & 3][col][k0];          \
        a1c0 = __builtin_amdgcn_mfma_f32_16x16x32_f16(wih0, axn, bias0, 0,0,0); \
        a1c1 = __builtin_amdgcn_mfma_f32_16x16x32_f16(wih1, axn, bias1, 0,0,0); \
        {   /* stage x(TT+3) -> xs ring; reload XREG = x(TT+5) */               \
            half2v hx;                                                          \
            hx[0] = (_Float16)XREG[0]; hx[1] = (_Float16)XREG[1];               \
            *(half2v*)&xs[((TT) + 3) & 3][sr][k2] = hx;                         \
            int tn = (TT) + 5; if (tn >= T_LEN) tn = T_LEN - 1;                 \
            XREG = *(const float2v*)(xsrc + (size_t)tn * 32);                   \
        }                                                                       \
        /* cell 0 (element e0): single-rcp fused c-update */                    \
        {                                                                       \
            const float Ai = __builtin_amdgcn_exp2f(acc0[0]);                   \
            const float Af = __builtin_amdgcn_exp2f(acc0[1]);                   \
            const float Bg = __builtin_amdgcn_exp2f(acc0[2]);                   \
            const float Ao = __builtin_amdgcn_exp2f(acc0[3]);                   \
            const float pI = 1.0f + Ai;                                         \
            const float pG = 1.0f + Bg;                                         \
            const float pF = 1.0f + Af;                                         \
            const float pIG = pI * pG;                                          \
            const float num = c0 * pIG + (Bg - 1.0f) * pF;                      \
            c0 = num * __builtin_amdgcn_rcpf(pF * pIG);                         \
            const float cc = fminf(fmaxf(c0, -16.0f), 16.0f);                   \
            const float C2 = __builtin_amdgcn_exp2f(cc * 2.88539008f);          \
            const float r3 = __builtin_amdgcn_rcpf((1.0f + Ao) * (1.0f + C2));  \
            hs[PPAR ^ 1][col][e0] = (_Float16)((C2 - 1.0f) * r3);               \
        }                                                                       \
        /* cell 1 (element e1) */                                               \
        {                                                                       \
            const float Ai = __builtin_amdgcn_exp2f(acc1[0]);                   \
            const float Af = __builtin_amdgcn_exp2f(acc1[1]);                   \
            const float Bg = __builtin_amdgcn_exp2f(acc1[2]);                   \
            const float Ao = __builtin_amdgcn_exp2f(acc1[3]);                   \
            const float pI = 1.0f + Ai;                                         \
            const float pG = 1.0f + Bg;                                         \
            const float pF = 1.0f + Af;                                         \
            const float pIG = pI * pG;                                          \
            const float num = c1 * pIG + (Bg - 1.0f) * pF;                      \
            c1 = num * __builtin_amdgcn_rcpf(pF * pIG);                         \
            const float cc = fminf(fmaxf(c1, -16.0f), 16.0f);                   \
            const float C2 = __builtin_amdgcn_exp2f(cc * 2.88539008f);          \
            const float r3 = __builtin_amdgcn_rcpf((1.0f + Ao) * (1.0f + C2));  \
            hs[PPAR ^ 1][col][e1] = (_Float16)((C2 - 1.0f) * r3);               \
        }                                                                       \
        __syncthreads();                                                        \
    }

    for (int t = 0; t < T_LEN; t += 2) {
        STEP(0, xA, t)
        STEP(1, xB, t + 1)
    }
    #undef STEP

    // ---- epilogue: h(511) was written to hs[0] (step 511 has parity 1)
    if (tid < ROWS) {
        float s = b_fc[0];
        #pragma unroll
        for (int cc2 = 0; cc2 < 32; ++cc2) {
            s += (float)hs[0][tid][cc2] * W_fc[cc2];
        }
        out[b0 + tid] = s;
    }
}

extern "C" void kernel_launch(void* const* d_in, const int* in_sizes, int n_in,
                              void* d_out, int out_size, void* d_ws, size_t ws_size,
                              hipStream_t stream) {
    const float* x    = (const float*)d_in[0];
    const float* W_ih = (const float*)d_in[1];
    const float* W_hh = (const float*)d_in[2];
    const float* b_ih = (const float*)d_in[3];
    const float* b_hh = (const float*)d_in[4];
    const float* W_fc = (const float*)d_in[5];
    const float* b_fc = (const float*)d_in[6];
    float* out = (float*)d_out;

    lstm_fused_kernel<<<dim3(NBLK), dim3(256), 0, stream>>>(
        x, W_ih, W_hh, b_ih, b_hh, W_fc, b_fc, out);
}

// Round 17
// 134.750 us; speedup vs baseline: 1.4089x; 1.0757x over previous
//
#include <hip/hip_runtime.h>
#include <stdint.h>

// PressureLSTM: B=4096, T=512, F=32, H=32, gates=128 (i,f,g,o).
// Swapped-MFMA, permuted gate index pg = e*4 + gtype (verified r5-r16):
//   mfma(A=W', B=X^T/H^T); lane's 4 acc regs = i,f,g,o of
//   (element e=4*wv+q, batch row col) -> lane-local cell update.
// r17 (from r11 base = 137us; r14/r15/r16 falsified vmcnt-drain, occupancy,
//   and LDS-bandwidth theories -> the wall is the serial per-step chain):
//   (1) DE-BURST: axn read + a1c MFMA + xs staging moved AFTER the hs write.
//       xs[(t+1)&3] was written at t-2 (visible), so it need not contend
//       with the 8 critical ah reads at barrier exit (16->8 b128 burst).
//   (2) cs-DOMAIN activation: cell state kept as cs = 2*log2e*c;
//       cs' = fma(cs, pIG, 2L*(Bg-1)*pF) * rcp(pF*pIG); C2 = exp2(clamp(cs'))
//       -- removes the post-clamp multiply from the h-critical chain and
//       overlaps rcp(den) with the num fma. Algebraically identical.
//   Everything else identical to r11: 8 waves, 16 real rows, xs[4] ring
//   staged 3 ahead, C-operand x-projection, f16 weights pre-scaled
//   -log2e (i,f,o) / +2log2e (g), one __syncthreads per step.

typedef _Float16 half8 __attribute__((ext_vector_type(8)));
typedef __attribute__((ext_vector_type(4))) float float4v;

#define T_LEN 512
#define B_ALL 4096
#define ROWS 16
#define NBLK (B_ALL / ROWS)   // 256 blocks -> 1 block/CU
#define P 40                  // f16 per LDS row (80 B pitch, b128-aligned)
#define CLAMP_CS 46.166f      // 16 * 2.88539 (tanh saturates, exp2 safe)

__global__ __launch_bounds__(512, 2) void lstm_fused_kernel(
    const float* __restrict__ x,     // [B, T, 32]
    const float* __restrict__ W_ih,  // [128, 32]
    const float* __restrict__ W_hh,  // [128, 32]
    const float* __restrict__ b_ih,  // [128]
    const float* __restrict__ b_hh,  // [128]
    const float* __restrict__ W_fc,  // [1, 32]
    const float* __restrict__ b_fc,  // [1]
    float* __restrict__ out)         // [B]
{
    const int tid  = threadIdx.x;    // 0..511
    const int wv   = tid >> 6;       // wave 0..7 (gate tile wv)
    const int lane = tid & 63;
    const int col  = lane & 15;      // batch row within tile (all real)
    const int q    = lane >> 4;      // 0..3
    const int k0   = q * 8;
    const int b0   = blockIdx.x * ROWS;
    const int e    = 4 * wv + q;     // this lane's h element (0..31)

    __shared__ __align__(16) _Float16 hs[2][ROWS][P];
    __shared__ __align__(16) _Float16 xs[4][ROWS][P];

    // ---- A-fragment weights, single f16 (RNE), pre-scaled per gate type:
    // lane holds W'[pg=16wv+col][k0..k0+7]; pg=e'*4+gt, e'=4wv+(col>>2), gt=col&3
    half8 wih, whh;
    {
        const int gt   = col & 3;
        const int gmem = gt * 32 + (4 * wv + (col >> 2));
        const float gs = (gt == 2) ? 2.88539008f : -1.44269504f;
        const float* wr = W_ih + gmem * 32 + k0;
        const float* hr = W_hh + gmem * 32 + k0;
        #pragma unroll
        for (int i = 0; i < 8; ++i) {
            wih[i] = (_Float16)(wr[i] * gs);
            whh[i] = (_Float16)(hr[i] * gs);
        }
    }
    // bias for acc reg r: gate type r of element e, same pre-scale
    float4v bias4;
    #pragma unroll
    for (int r = 0; r < 4; ++r) {
        const float gsr = (r == 2) ? 2.88539008f : -1.44269504f;
        bias4[r] = (b_ih[r * 32 + e] + b_hh[r * 32 + e]) * gsr;
    }

    float cs = 0.f;   // cell state in scaled domain: cs = 2*log2e * c

    // ---- x staging: all 512 threads cover 16 rows x 32 k, one float each
    const int sr = tid >> 5;         // staged row 0..15
    const int sk = tid & 31;         // k element
    const float* xsrc = x + ((size_t)(b0 + sr) * T_LEN) * 32 + sk;

    // prologue: prime xs[0..2] with x(0..2); h(-1)=0; FIFO xA=x(3), xB=x(4)
    float xA, xB;
    {
        xs[0][sr][sk] = (_Float16)xsrc[0];
        xs[1][sr][sk] = (_Float16)xsrc[32];
        xs[2][sr][sk] = (_Float16)xsrc[64];
        hs[0][sr][sk] = (_Float16)0.f;
        xA = xsrc[3 * 32];
        xB = xsrc[4 * 32];
    }
    __syncthreads();

    // a1c for t=0 (x-side acc, bias folded as C)
    float4v a1c;
    {
        const half8 ax0 = *(const half8*)&xs[0][col][k0];
        a1c = __builtin_amdgcn_mfma_f32_16x16x32_f16(wih, ax0, bias4, 0, 0, 0);
    }

    // step t (hs parity PPAR=t&1): reads hs[PPAR], writes hs[PPAR^1].
    // Chain: ds_read(ah) -> mfma(whh,ah,C=a1c) -> cs-domain act -> hs write.
    // Off-chain (after hs write): axn read, a1c MFMA, xs stage, x load.
    #define STEP(PPAR, XREG, TT)                                                \
    {                                                                           \
        const half8 ah = *(const half8*)&hs[PPAR][col][k0];   /* critical */    \
        const float4v acc =                                                     \
            __builtin_amdgcn_mfma_f32_16x16x32_f16(whh, ah, a1c, 0, 0, 0);      \
        /* cs-domain fused activations:                                      */ \
        /* cs' = fma(cs, pIG, 2L*(Bg-1)*pF) * rcp(pF*pIG); C2=exp2(clamp)   */  \
        const float Ai = __builtin_amdgcn_exp2f(acc[0]);                        \
        const float Af = __builtin_amdgcn_exp2f(acc[1]);                        \
        const float Bg = __builtin_amdgcn_exp2f(acc[2]);                        \
        const float Ao = __builtin_amdgcn_exp2f(acc[3]);                        \
        const float pI = 1.0f + Ai;                                             \
        const float pG = 1.0f + Bg;                                             \
        const float pF = 1.0f + Af;                                             \
        const float pIG = pI * pG;                                              \
        const float t2  = 2.88539008f * (Bg - 1.0f) * pF;                       \
        const float rden = __builtin_amdgcn_rcpf(pF * pIG);                     \
        const float num = __builtin_fmaf(cs, pIG, t2);                          \
        cs = num * rden;                                                        \
        const float ccs = fminf(fmaxf(cs, -CLAMP_CS), CLAMP_CS);                \
        const float C2 = __builtin_amdgcn_exp2f(ccs);                           \
        const float r3 = __builtin_amdgcn_rcpf((1.0f + Ao) * (1.0f + C2));      \
        const float hv = (C2 - 1.0f) * r3;                                      \
        hs[PPAR ^ 1][col][e] = (_Float16)hv;                                    \
        /* ---- off-chain work (fills write-retire + barrier window) ---- */    \
        const half8 axn = *(const half8*)&xs[((TT) + 1) & 3][col][k0];          \
        a1c = __builtin_amdgcn_mfma_f32_16x16x32_f16(wih, axn, bias4, 0, 0, 0); \
        xs[((TT) + 3) & 3][sr][sk] = (_Float16)XREG;                            \
        {                                                                       \
            int tn = (TT) + 5; if (tn >= T_LEN) tn = T_LEN - 1;                 \
            XREG = xsrc[(size_t)tn * 32];                                       \
        }                                                                       \
        __syncthreads();                                                        \
    }

    for (int t = 0; t < T_LEN; t += 2) {
        STEP(0, xA, t)
        STEP(1, xB, t + 1)
    }
    #undef STEP

    // ---- epilogue: h(511) was written to hs[0] (step 511 has parity 1)
    if (tid < ROWS) {
        float s = b_fc[0];
        #pragma unroll
        for (int cc2 = 0; cc2 < 32; ++cc2) {
            s += (float)hs[0][tid][cc2] * W_fc[cc2];
        }
        out[b0 + tid] = s;
    }
}

extern "C" void kernel_launch(void* const* d_in, const int* in_sizes, int n_in,
                              void* d_out, int out_size, void* d_ws, size_t ws_size,
                              hipStream_t stream) {
    const float* x    = (const float*)d_in[0];
    const float* W_ih = (const float*)d_in[1];
    const float* W_hh = (const float*)d_in[2];
    const float* b_ih = (const float*)d_in[3];
    const float* b_hh = (const float*)d_in[4];
    const float* W_fc = (const float*)d_in[5];
    const float* b_fc = (const float*)d_in[6];
    float* out = (float*)d_out;

    lstm_fused_kernel<<<dim3(NBLK), dim3(512), 0, stream>>>(
        x, W_ih, W_hh, b_ih, b_hh, W_fc, b_fc, out);
}